// Round 14
// baseline (102.423 us; speedup 1.0000x reference)
//
#include <hip/hip_runtime.h>
#include <cstdint>

typedef __bf16 bf16;
typedef __bf16 bf16x2 __attribute__((ext_vector_type(2)));
typedef __bf16 bf16x4 __attribute__((ext_vector_type(4)));
typedef __bf16 bf16x8 __attribute__((ext_vector_type(8)));
typedef float f32x4 __attribute__((ext_vector_type(4)));

constexpr int S = 2048, D = 1024, H = 16, HD = 64, B = 2;
constexpr size_t TSZ = (size_t)B * H * S * HD;  // 4 Mi elements

__device__ __forceinline__ f32x4 mfma16(bf16x8 a, bf16x8 b, f32x4 c) {
  return __builtin_amdgcn_mfma_f32_16x16x32_bf16(a, b, c, 0, 0, 0);
}

// async global->LDS, 16B per lane. LDS dest = wave-linear (base + lane*16).
__device__ __forceinline__ void gl_lds16(const bf16* g, bf16* s) {
  __builtin_amdgcn_global_load_lds((__attribute__((address_space(1))) void*)g,
                                   (__attribute__((address_space(3))) void*)s,
                                   16, 0, 0);
}

// ---------------------------------------------------------------------------
// prep (merged): blocks 0..2047 convert x fp32->bf16; blocks 2048..3071
// transpose W [K][N] fp32 -> Wt [z][N][K] bf16 via 64x64 LDS tiles.
// ---------------------------------------------------------------------------
__global__ __launch_bounds__(256) void prep_all(const float* __restrict__ x,
                                                const float* __restrict__ W0,
                                                const float* __restrict__ W1,
                                                const float* __restrict__ W2,
                                                const float* __restrict__ W3,
                                                bf16* __restrict__ xb,
                                                bf16* __restrict__ Wt) {
  __shared__ __align__(16) bf16 Lt[64][68];
  const int bid = blockIdx.x, t = threadIdx.x;
  if (bid < 2048) {
    const size_t i = (size_t)bid * 256 + t;
    const float4 a = ((const float4*)x)[2 * i];
    const float4 b = ((const float4*)x)[2 * i + 1];
    bf16x8 o = {(bf16)a.x, (bf16)a.y, (bf16)a.z, (bf16)a.w,
                (bf16)b.x, (bf16)b.y, (bf16)b.z, (bf16)b.w};
    *(bf16x8*)&xb[i * 8] = o;
    return;
  }
  const int r = bid - 2048;
  const int z = r >> 8, rest = r & 255;
  const float* W = z == 0 ? W0 : z == 1 ? W1 : z == 2 ? W2 : W3;
  const int k0 = (rest & 15) * 64, n0 = (rest >> 4) * 64;
  const int tr = t >> 4, tc = (t & 15) * 4;
#pragma unroll
  for (int p = 0; p < 4; ++p) {
    const int rr = 16 * p + tr;
    const float4 v = *(const float4*)&W[(size_t)(k0 + rr) * D + n0 + tc];
    Lt[tc + 0][rr] = (bf16)v.x;
    Lt[tc + 1][rr] = (bf16)v.y;
    Lt[tc + 2][rr] = (bf16)v.z;
    Lt[tc + 3][rr] = (bf16)v.w;
  }
  __syncthreads();
#pragma unroll
  for (int p = 0; p < 4; ++p) {
    const int n = 16 * p + tr;
    const bf16x4 o = *(const bf16x4*)&Lt[n][tc];
    *(bf16x4*)&Wt[((size_t)z * D + n0 + n) * D + k0 + tc] = o;
  }
}

// ---------------------------------------------------------------------------
// bf16 GEMM, m97 structure: BM=128 x BNT tile, BK=64, 4 waves,
// global_load_lds staging with XOR-preswizzled source, swizzled b128 frags.
// ---------------------------------------------------------------------------
template <int MODE, int BNT>
__global__ __launch_bounds__(256) void gemm_bt(const bf16* __restrict__ A,
                                               const bf16* __restrict__ Bt,
                                               void* __restrict__ Cp) {
  constexpr int K = 1024;
  constexpr int NI = BNT / 32;            // n-frags per wave (4 or 2)
  __shared__ __align__(16) bf16 As[128 * 64];
  __shared__ __align__(16) bf16 Bs[BNT * 64];

  const int bid = blockIdx.x, nwg = gridDim.x;       // nwg % 8 == 0
  const int lg = (bid & 7) * (nwg >> 3) + (bid >> 3);  // XCD-chunked
  const int bm = (lg & 31) * 128;
  const int bn = (lg >> 5) * BNT;

  const int t = threadIdx.x, l = t & 63, w = t >> 6;
  const int c = l & 15, g = l >> 4, cx = c & 7;
  const int lrow = l >> 3;                  // row within 1KB LDS chunk
  const int srcc = ((l & 7) ^ lrow) << 3;   // pre-swizzled source k-offset
  const int wm = (w >> 1) * 64, wn = (w & 1) * (BNT / 2);

  f32x4 acc[4][NI] = {};

  for (int kt = 0; kt < K / 64; ++kt) {
    const int k0 = kt * 64;
    __syncthreads();  // prior compute done before overwrite
#pragma unroll
    for (int i = 0; i < 4; ++i) {
      const int ci = i * 4 + w;         // 1KB chunk id (16 per 128-row tile)
      const int row = ci * 8 + lrow;    // tile row 0..127
      gl_lds16(A + (size_t)(bm + row) * K + k0 + srcc, As + ci * 512 + l * 8);
    }
#pragma unroll
    for (int i = 0; i < BNT / 32; ++i) {
      const int ci = i * 4 + w;         // BNT/8 chunks of 1KB
      const int row = ci * 8 + lrow;
      gl_lds16(Bt + (size_t)(bn + row) * K + k0 + srcc, Bs + ci * 512 + l * 8);
    }
    __syncthreads();  // drains vmcnt

    bf16x8 af[4][2], bfv[NI][2];
#pragma unroll
    for (int mi = 0; mi < 4; ++mi) {
      const int row = wm + mi * 16 + c;  // row&7 == cx
#pragma unroll
      for (int kh = 0; kh < 2; ++kh)
        af[mi][kh] = *(const bf16x8*)&As[row * 64 + (((kh * 4 + g) ^ cx) << 3)];
    }
#pragma unroll
    for (int ni = 0; ni < NI; ++ni) {
      const int row = wn + ni * 16 + c;
#pragma unroll
      for (int kh = 0; kh < 2; ++kh)
        bfv[ni][kh] = *(const bf16x8*)&Bs[row * 64 + (((kh * 4 + g) ^ cx) << 3)];
    }
#pragma unroll
    for (int mi = 0; mi < 4; ++mi)
#pragma unroll
      for (int ni = 0; ni < NI; ++ni) {
        acc[mi][ni] = mfma16(af[mi][0], bfv[ni][0], acc[mi][ni]);
        acc[mi][ni] = mfma16(af[mi][1], bfv[ni][1], acc[mi][ni]);
      }
  }

  // epilogue: C frag row = 4g+r, col = c (verified mapping)
#pragma unroll
  for (int mi = 0; mi < 4; ++mi)
#pragma unroll
    for (int ni = 0; ni < NI; ++ni)
#pragma unroll
      for (int r = 0; r < 4; ++r) {
        const int m = bm + wm + mi * 16 + 4 * g + r;
        const int n = bn + wn + ni * 16 + c;
        const float v = acc[mi][ni][r];
        if constexpr (MODE == 0) {
          const int which = n >> 10, nn = n & 1023;
          const int h = nn >> 6, d = nn & 63;
          const int bb = m >> 11, s = m & 2047;
          ((bf16*)Cp)[which * TSZ + ((((size_t)bb * H + h) * S + s) << 6) + d] =
              (bf16)v;
        } else {
          ((float*)Cp)[(size_t)m * D + n] = v;
        }
      }
}

// ---------------------------------------------------------------------------
// Flash attention v14: 32 Q-ROWS PER WAVE (K/V frags read once, reused for
// two Q-frags -> LDS cycles per q-row HALVED) + r10 split-kv geometry
// (max 16 iters on the chain) + double-buffered K DMA (issued one tile early;
// completion guaranteed by compiler's reg-dependency vmcnt wait before
// barrier B; sched_barrier pins DMA-before-V-load issue order).
// Items per bh (24): e<16: tile j=15-(e>>1) (128 q-rows), kv-half e&1
// (j+1 iters, 9..16); e>=16: tile j=e-16 single (2j+2 iters, 2..16).
// 768 blocks = 3/CU x 4 waves = 12 waves/CU. LDS 24KB (Ks dbuf 16K + Vt 8K).
// Rows < 1024: direct bf16 out. Rows >= 1024: normalized-bf16 partials + m,l
// -> attn_merge2. All fragment layouts verbatim from verified kernels.
// ---------------------------------------------------------------------------
__global__ __launch_bounds__(256, 3) void attn14(const bf16* __restrict__ Q,
                                                 const bf16* __restrict__ Kg,
                                                 const bf16* __restrict__ Vg,
                                                 bf16* __restrict__ Ab,
                                                 bf16* __restrict__ Op,
                                                 float* __restrict__ ML) {
  __shared__ __align__(16) bf16 Ks[2 * 64 * 64];  // double-buffered K
  __shared__ __align__(16) bf16 Vt[64 * 64];      // [vd][kv-permuted]

  const int bid = blockIdx.x;
  const int e = bid >> 5, bh = bid & 31;   // same-bh blocks share an XCD
  int j, kvA, kvB, half;
  bool split;
  if (e < 16) {
    j = 15 - (e >> 1); half = e & 1; split = true;
    kvA = half * (j + 1); kvB = kvA + (j + 1);
  } else {
    j = e - 16; half = 0; split = false;
    kvA = 0; kvB = 2 * j + 2;
  }

  const int t = threadIdx.x, l = t & 63, w = t >> 6;
  const int c = l & 15, g = l >> 4, cx = c & 7;
  const int bb = bh >> 4, h = bh & 15;
  const float SC = 0.18033688011112042f;   // (1/8)*log2(e)
  const float THRS = 44.3614195558365f;    // 8 / SC (defer-max threshold)

  const bf16* Kbase = Kg + (size_t)bh * S * HD;
  const bf16* Vbase = Vg + (size_t)bh * S * HD;

  const int q0 = j * 128;
  const int qga = q0 + 32 * w + c;       // subtile a rows
  const int qgb = qga + 16;              // subtile b rows
  const bf16* Qa = Q + ((size_t)bh * S + qga) * HD;
  const bf16* Qb = Q + ((size_t)bh * S + qgb) * HD;
  const bf16x8 qfa0 = *(const bf16x8*)&Qa[g * 8];
  const bf16x8 qfa1 = *(const bf16x8*)&Qa[32 + g * 8];
  const bf16x8 qfb0 = *(const bf16x8*)&Qb[g * 8];
  const bf16x8 qfb1 = *(const bf16x8*)&Qb[32 + g * 8];

  // K DMA map (gemm-verified): 8 chunks of 1KB; this thread does w and 4+w
  const int lrow = l >> 3;
  const int srcc = ((l & 7) ^ lrow) << 3;
  // V staging map (r10-verified kv-permuted layout)
  const int p2 = t & 31, dgv = t >> 5;
  const int hv = p2 >> 4;
  const int gv = (p2 >> 1) & 3;
  const int jv = ((p2 >> 3) & 1) * 4 + (p2 & 1) * 2;
  const int vchunk = (hv << 2) | gv;

  // ---- prologue: K(kvA) DMA first, then V(kvA) regs (order pinned) ----
  {
    const bf16* K0 = Kbase + (size_t)kvA * 64 * HD;
    bf16* kd = Ks + (kvA & 1) * 4096;
    gl_lds16(K0 + (size_t)(w * 8 + lrow) * 64 + srcc, kd + w * 512 + l * 8);
    gl_lds16(K0 + (size_t)((4 + w) * 8 + lrow) * 64 + srcc,
             kd + (4 + w) * 512 + l * 8);
  }
  __builtin_amdgcn_sched_barrier(0);
  bf16x8 va0 = *(const bf16x8*)&Vbase[((size_t)kvA * 64 + 2 * p2) * 64 + dgv * 8];
  bf16x8 va1 = *(const bf16x8*)&Vbase[((size_t)kvA * 64 + 2 * p2 + 1) * 64 + dgv * 8];

  f32x4 oacc_a[4] = {}, oacc_b[4] = {};
  float mrun_a = -1e30f, lrun_a = 0.f;
  float mrun_b = -1e30f, lrun_b = 0.f;

  for (int kt = kvA; kt < kvB; ++kt) {
    // ---- barrier A: all waves done reading previous tile's LDS ----
    __builtin_amdgcn_s_barrier();
    __builtin_amdgcn_sched_barrier(0);

    // ---- issue NEXT K tile DMA into the other buffer ----
    if (kt + 1 < kvB) {
      const bf16* Kn = Kbase + (size_t)(kt + 1) * 64 * HD;
      bf16* kd = Ks + ((kt + 1) & 1) * 4096;
      gl_lds16(Kn + (size_t)(w * 8 + lrow) * 64 + srcc, kd + w * 512 + l * 8);
      gl_lds16(Kn + (size_t)((4 + w) * 8 + lrow) * 64 + srcc,
               kd + (4 + w) * 512 + l * 8);
    }
    __builtin_amdgcn_sched_barrier(0);  // pin: K-DMA before V write/loads

    // ---- write current V regs -> LDS (kv-permuted; reg-dep vmcnt wait
    //      here also drains this tile's K DMA, issued last iteration) ----
#pragma unroll
    for (int i = 0; i < 8; ++i) {
      bf16x2 pr2 = {va0[i], va1[i]};
      *(bf16x2*)&Vt[(8 * dgv + i) * 64 + ((vchunk ^ i) << 3) + jv] = pr2;
    }
    // ---- next V loads (clamped; stay in flight across barrier B) ----
    {
      const int ktn = (kt + 1 < kvB) ? kt + 1 : kt;
      const bf16* Vs = Vbase + (size_t)ktn * 64 * HD;
      va0 = *(const bf16x8*)&Vs[(2 * p2) * 64 + dgv * 8];
      va1 = *(const bf16x8*)&Vs[(2 * p2 + 1) * 64 + dgv * 8];
    }
    // ---- barrier B: V LDS writes visible; next loads not drained ----
    asm volatile("s_waitcnt lgkmcnt(0)" ::: "memory");
    __builtin_amdgcn_s_barrier();
    __builtin_amdgcn_sched_barrier(0);

    const bf16* kbuf = Ks + (kt & 1) * 4096;

    // ---- S^T = K Q^T for BOTH q-subtiles (K frags read once) ----
    f32x4 st_a[4], st_b[4];
    __builtin_amdgcn_s_setprio(1);
#pragma unroll
    for (int ct = 0; ct < 4; ++ct) {
      const int krow = ct * 16 + c;  // krow&7 == cx
      const bf16x8 kf0 = *(const bf16x8*)&kbuf[krow * 64 + ((g ^ cx) << 3)];
      const bf16x8 kf1 = *(const bf16x8*)&kbuf[krow * 64 + (((4 + g) ^ cx) << 3)];
      f32x4 za = {}, zb = {};
      za = mfma16(kf0, qfa0, za);
      st_a[ct] = mfma16(kf1, qfa1, za);
      zb = mfma16(kf0, qfb0, zb);
      st_b[ct] = mfma16(kf1, qfb1, zb);
    }
    __builtin_amdgcn_s_setprio(0);

    // ---- causal mask (wave-uniform gate; last 1-2 iterations only) ----
    if (64 * kt + 63 > q0 + 32 * w) {
#pragma unroll
      for (int ct = 0; ct < 4; ++ct)
#pragma unroll
        for (int r = 0; r < 4; ++r) {
          const int kv = kt * 64 + ct * 16 + 4 * g + r;
          if (kv > qga) st_a[ct][r] = -1e30f;
          if (kv > qgb) st_b[ct][r] = -1e30f;
        }
    }

    // ---- in-lane online softmax x2 (tree max, defer-max) ----
    {
      float tm[4];
#pragma unroll
      for (int ct = 0; ct < 4; ++ct)
        tm[ct] = fmaxf(fmaxf(st_a[ct][0], st_a[ct][1]),
                       fmaxf(st_a[ct][2], st_a[ct][3]));
      float mt = fmaxf(fmaxf(tm[0], tm[1]), fmaxf(tm[2], tm[3]));
      mt = fmaxf(mt, __shfl_xor(mt, 16));
      mt = fmaxf(mt, __shfl_xor(mt, 32));
      if (!__all(mt <= mrun_a + THRS)) {
        const float mnew = fmaxf(mrun_a, mt);
        const float fac = __builtin_amdgcn_exp2f((mrun_a - mnew) * SC);
        lrun_a *= fac;
#pragma unroll
        for (int ct = 0; ct < 4; ++ct)
#pragma unroll
          for (int r = 0; r < 4; ++r) oacc_a[ct][r] *= fac;
        mrun_a = mnew;
      }
    }
    {
      float tm[4];
#pragma unroll
      for (int ct = 0; ct < 4; ++ct)
        tm[ct] = fmaxf(fmaxf(st_b[ct][0], st_b[ct][1]),
                       fmaxf(st_b[ct][2], st_b[ct][3]));
      float mt = fmaxf(fmaxf(tm[0], tm[1]), fmaxf(tm[2], tm[3]));
      mt = fmaxf(mt, __shfl_xor(mt, 16));
      mt = fmaxf(mt, __shfl_xor(mt, 32));
      if (!__all(mt <= mrun_b + THRS)) {
        const float mnew = fmaxf(mrun_b, mt);
        const float fac = __builtin_amdgcn_exp2f((mrun_b - mnew) * SC);
        lrun_b *= fac;
#pragma unroll
        for (int ct = 0; ct < 4; ++ct)
#pragma unroll
          for (int r = 0; r < 4; ++r) oacc_b[ct][r] *= fac;
        mrun_b = mnew;
      }
    }
    float pa[4][4], pb[4][4];
    float sqa[4], sqb[4];
#pragma unroll
    for (int ct = 0; ct < 4; ++ct) {
#pragma unroll
      for (int r = 0; r < 4; ++r) {
        pa[ct][r] = __builtin_amdgcn_exp2f((st_a[ct][r] - mrun_a) * SC);
        pb[ct][r] = __builtin_amdgcn_exp2f((st_b[ct][r] - mrun_b) * SC);
      }
      sqa[ct] = (pa[ct][0] + pa[ct][1]) + (pa[ct][2] + pa[ct][3]);
      sqb[ct] = (pb[ct][0] + pb[ct][1]) + (pb[ct][2] + pb[ct][3]);
    }
    lrun_a += (sqa[0] + sqa[1]) + (sqa[2] + sqa[3]);
    lrun_b += (sqb[0] + sqb[1]) + (sqb[2] + sqb[3]);

    // ---- P in-register (r10-verified slot mapping) ----
    const bf16x8 pa0_a = {(bf16)pa[0][0], (bf16)pa[0][1], (bf16)pa[0][2], (bf16)pa[0][3],
                          (bf16)pa[1][0], (bf16)pa[1][1], (bf16)pa[1][2], (bf16)pa[1][3]};
    const bf16x8 pa1_a = {(bf16)pa[2][0], (bf16)pa[2][1], (bf16)pa[2][2], (bf16)pa[2][3],
                          (bf16)pa[3][0], (bf16)pa[3][1], (bf16)pa[3][2], (bf16)pa[3][3]};
    const bf16x8 pa0_b = {(bf16)pb[0][0], (bf16)pb[0][1], (bf16)pb[0][2], (bf16)pb[0][3],
                          (bf16)pb[1][0], (bf16)pb[1][1], (bf16)pb[1][2], (bf16)pb[1][3]};
    const bf16x8 pa1_b = {(bf16)pb[2][0], (bf16)pb[2][1], (bf16)pb[2][2], (bf16)pb[2][3],
                          (bf16)pb[3][0], (bf16)pb[3][1], (bf16)pb[3][2], (bf16)pb[3][3]};

    // ---- O^T += V^T P^T for both subtiles (V frags read once) ----
    __builtin_amdgcn_s_setprio(1);
#pragma unroll
    for (int ct = 0; ct < 4; ++ct) {
      const int vrow = ct * 16 + c;
      const bf16x8 vt0 = *(const bf16x8*)&Vt[vrow * 64 + ((g ^ cx) << 3)];
      const bf16x8 vt1 = *(const bf16x8*)&Vt[vrow * 64 + (((4 + g) ^ cx) << 3)];
      oacc_a[ct] = mfma16(vt0, pa0_a, oacc_a[ct]);
      oacc_a[ct] = mfma16(vt1, pa1_a, oacc_a[ct]);
      oacc_b[ct] = mfma16(vt0, pa0_b, oacc_b[ct]);
      oacc_b[ct] = mfma16(vt1, pa1_b, oacc_b[ct]);
    }
    __builtin_amdgcn_s_setprio(0);
  }

  // ---- epilogue: reduce l per subtile, store ----
  float lt_a = lrun_a, lt_b = lrun_b;
  lt_a += __shfl_xor(lt_a, 16); lt_a += __shfl_xor(lt_a, 32);
  lt_b += __shfl_xor(lt_b, 16); lt_b += __shfl_xor(lt_b, 32);
  const float inva = 1.f / lt_a, invb = 1.f / lt_b;

  if (!split) {
    bf16* Oa = Ab + ((size_t)bb * S + qga) * D + h * 64;
    bf16* Ob = Ab + ((size_t)bb * S + qgb) * D + h * 64;
#pragma unroll
    for (int ct = 0; ct < 4; ++ct)
#pragma unroll
      for (int pr = 0; pr < 2; ++pr) {
        bf16x2 ka = {(bf16)(oacc_a[ct][2 * pr] * inva),
                     (bf16)(oacc_a[ct][2 * pr + 1] * inva)};
        bf16x2 kb = {(bf16)(oacc_b[ct][2 * pr] * invb),
                     (bf16)(oacc_b[ct][2 * pr + 1] * invb)};
        *(bf16x2*)&Oa[ct * 16 + 4 * g + 2 * pr] = ka;
        *(bf16x2*)&Ob[ct * 16 + 4 * g + 2 * pr] = kb;
      }
  } else {
    // rows >= 1024 by construction (j >= 8)
    const size_t ra = ((size_t)bh * 1024 + (qga - 1024)) * 2 + half;
    const size_t rb = ((size_t)bh * 1024 + (qgb - 1024)) * 2 + half;
    bf16* Pa = Op + ra * 64;
    bf16* Pb = Op + rb * 64;
#pragma unroll
    for (int ct = 0; ct < 4; ++ct)
#pragma unroll
      for (int pr = 0; pr < 2; ++pr) {
        bf16x2 ka = {(bf16)(oacc_a[ct][2 * pr] * inva),
                     (bf16)(oacc_a[ct][2 * pr + 1] * inva)};
        bf16x2 kb = {(bf16)(oacc_b[ct][2 * pr] * invb),
                     (bf16)(oacc_b[ct][2 * pr + 1] * invb)};
        *(bf16x2*)&Pa[ct * 16 + 4 * g + 2 * pr] = ka;
        *(bf16x2*)&Pb[ct * 16 + 4 * g + 2 * pr] = kb;
      }
    if (g == 0) {
      ML[ra * 2] = mrun_a; ML[ra * 2 + 1] = lt_a;
      ML[rb * 2] = mrun_b; ML[rb * 2 + 1] = lt_b;
    }
  }
}

// ---------------------------------------------------------------------------
// Merge split-kv partials (rows 1024..2047 of every bh) -> Ab bf16.
// One wave per row; partials are self-normalized bf16 + (m, l) f32.
// ---------------------------------------------------------------------------
__global__ __launch_bounds__(256) void attn_merge2(const bf16* __restrict__ Op,
                                                   const float* __restrict__ ML,
                                                   bf16* __restrict__ Ab) {
  const float SC = 0.18033688011112042f;
  const int rid = blockIdx.x * 4 + (threadIdx.x >> 6);  // 0..32767
  const int lane = threadIdx.x & 63;
  const int bh = rid >> 10, rw = rid & 1023;
  const size_t r2 = (size_t)rid * 2;
  const float m0 = ML[(r2 + 0) * 2], l0 = ML[(r2 + 0) * 2 + 1];
  const float m1 = ML[(r2 + 1) * 2], l1 = ML[(r2 + 1) * 2 + 1];
  const float o0 = (float)Op[(r2 + 0) * 64 + lane];
  const float o1 = (float)Op[(r2 + 1) * 64 + lane];
  const float mn = fmaxf(m0, m1);
  const float w0 = l0 * exp2f((m0 - mn) * SC);
  const float w1 = l1 * exp2f((m1 - mn) * SC);
  const float o = (o0 * w0 + o1 * w1) / (w0 + w1);
  const int bb = bh >> 4, h = bh & 15, s = 1024 + rw;
  Ab[((size_t)bb * S + s) * D + h * 64 + lane] = (bf16)o;
}

// ---------------------------------------------------------------------------
extern "C" void kernel_launch(void* const* d_in, const int* in_sizes, int n_in,
                              void* d_out, int out_size, void* d_ws, size_t ws_size,
                              hipStream_t stream) {
  const float* x  = (const float*)d_in[0];
  const float* Wq = (const float*)d_in[1];
  const float* Wk = (const float*)d_in[2];
  const float* Wv = (const float*)d_in[3];
  const float* Wo = (const float*)d_in[4];
  float* out = (float*)d_out;

  bf16* xb  = (bf16*)d_ws;                       // 4Mi  (8 MB)
  bf16* Wt  = xb + (size_t)B * S * D;            // 4Mi  (8 MB) [4][1024][1024]
  bf16* QKV = Wt + (size_t)4 * D * D;            // 12Mi (24 MB) [3][B,H,S,Dh]
  bf16* Ab  = QKV + 3 * TSZ;                     // 4Mi  (8 MB) [B*S][D]
  bf16* Op  = Ab + TSZ;                          // 32*1024*2*64 bf16 (8 MB)
  float* ML = (float*)(Op + (size_t)32 * 1024 * 2 * 64);  // 256 K f32 (1 MB)

  prep_all<<<3072, 256, 0, stream>>>(x, Wq, Wk, Wv, Wo, xb, Wt);
  gemm_bt<0, 128><<<768, 256, 0, stream>>>(xb, Wt, QKV);             // fused QKV
  attn14<<<768, 256, 0, stream>>>(QKV, QKV + TSZ, QKV + 2 * TSZ, Ab, Op, ML);
  attn_merge2<<<8192, 256, 0, stream>>>(Op, ML, Ab);
  gemm_bt<1, 64><<<512, 256, 0, stream>>>(Ab, Wt + (size_t)3 * D * D, out);
}